// Round 4
// baseline (274.888 us; speedup 1.0000x reference)
//
#include <hip/hip_runtime.h>

// BrickVectorEdgeModel on MI355X (gfx950).
// R11: (a) prep kernel DELETED -- node kernels read fp32 weights directly,
// converting in-register via v_cvt_pk_bf16_f32 (RNE-identical to prep's
// f2bf, so numerics unchanged); edge-weight tiled conversion (Wcb/Wcc/Wout)
// folded into node1 as a grid-stride side job. Kills 1 launch + 1 dep gap +
// prep's read of node weights. (b) edge gemm_kloop W prefetch deepened to a
// 3-slot ring (2 ks-steps in flight): R10 accounting showed W-from-L2
// (~48k cyc/block) and MFMA (~45k) nearly SERIALIZED (93.5k total); 1-deep
// prefetch forces vmcnt(0) drain each ks. 2-deep lets loads span ks-steps.
// Node stage restored to R7's proven col-tiled 3-kernel structure
// (96/96/192 blocks) -- R8's 24-block fusion was W-stream-bound.
// Tiled W layout (per 512-col weight, elems): off(c,k) =
//   ((c>>4)*16 + (k>>5))*512 + (c&15)*32 + (k&31)

typedef short  short8  __attribute__((ext_vector_type(8)));
typedef short  short4v __attribute__((ext_vector_type(4)));
typedef float  f32x4   __attribute__((ext_vector_type(4)));

#define LDSW 520   // LDS row stride in bf16 elems (520*2B = 1040B, 16B-aligned)

__device__ inline unsigned short f2bf(float x) {
  unsigned u = __float_as_uint(x);
  unsigned r = (u + 0x7FFFu + ((u >> 16) & 1u)) >> 16;  // RNE
  return (unsigned short)r;
}

// v_cvt_pk_bf16_f32: D[15:0]=bf16(S0) RNE, D[31:16]=bf16(S1).
__device__ inline unsigned cvt_pk_bf16(float lo, float hi) {
  unsigned d;
  asm("v_cvt_pk_bf16_f32 %0, %1, %2" : "=v"(d) : "v"(lo), "v"(hi));
  return d;
}
// relu+pack 4 floats -> 2 dwords of bf16
__device__ inline uint2 relu_pack4(float x0, float x1, float x2, float x3) {
  uint2 s;
  s.x = cvt_pk_bf16(fmaxf(x0, 0.f), fmaxf(x1, 0.f));
  s.y = cvt_pk_bf16(fmaxf(x2, 0.f), fmaxf(x3, 0.f));
  return s;
}

__device__ __host__ inline int wtile_off(int c, int k) {
  return ((c >> 4) * 16 + (k >> 5)) * 512 + (c & 15) * 32 + (k & 31);
}

template <int MT, int NT>
__device__ inline void zero_acc(f32x4 (&acc)[MT][NT]) {
#pragma unroll
  for (int mt = 0; mt < MT; ++mt)
#pragma unroll
    for (int nt = 0; nt < NT; ++nt) {
      f32x4 z = {0.f, 0.f, 0.f, 0.f};
      acc[mt][nt] = z;
    }
}

// Edge GEMM k-loop: tiled bf16 W, 3-slot ring W prefetch (2 ks in flight).
// W as MFMA A-operand (lane&15 = out-col within 16-tile, lane>>4 = k-group);
// E as B-operand (lane&15 = edge-row). One wF load = coalesced 1KB.
template <int MT, int NT>
__device__ inline void gemm_kloop(const short* E, const short* __restrict__ W,
                                  int lane, int nbase, f32x4 (&acc)[MT][NT]) {
  const int mrow = lane & 15, kg = lane >> 4;
  const short* El = E + mrow * LDSW + kg * 8;
  const short* Wl = W + (nbase >> 4) * 8192 + mrow * 32 + kg * 8;
  short8 wF[3][NT];
#pragma unroll
  for (int nt = 0; nt < NT; ++nt) {
    wF[0][nt] = *(const short8*)(Wl + nt * 8192);
    wF[1][nt] = *(const short8*)(Wl + nt * 8192 + 512);
  }
#pragma unroll
  for (int ks = 0; ks < 16; ++ks) {
    const int cur = ks % 3;
    if (ks < 14) {
      const int nx2 = (ks + 2) % 3, k2 = (ks + 2) * 512;
#pragma unroll
      for (int nt = 0; nt < NT; ++nt)
        wF[nx2][nt] = *(const short8*)(Wl + nt * 8192 + k2);
    }
    const int k0 = ks * 32;
    short8 e0 = *(const short8*)(El + k0);
#pragma unroll
    for (int mt = 0; mt < MT; ++mt) {
      const short8 ecur = e0;
      if (mt < MT - 1) e0 = *(const short8*)(El + (mt + 1) * 16 * LDSW + k0);
#pragma unroll
      for (int nt = 0; nt < NT; ++nt)
        acc[mt][nt] = __builtin_amdgcn_mfma_f32_16x16x32_bf16(
            wF[cur][nt], ecur, acc[mt][nt], 0, 0, 0);
    }
  }
}

// Node GEMM k-loop: W read DIRECTLY from fp32 row-major global (stride
// WSTRIDE), double-buffered in f32 regs, converted to bf16 in-register.
// Same lane mapping as gemm_kloop. NT=1.
template <int MT, int WSTRIDE>
__device__ inline void gemm_kloop_wf32(const short* E, const float* __restrict__ W,
                                       int lane, int colbase, f32x4 (&acc)[MT][1]) {
  const int mrow = lane & 15, kg = lane >> 4;
  const short* El = E + mrow * LDSW + kg * 8;
  const float* Wl = W + (colbase + mrow) * WSTRIDE + kg * 8;
  f32x4 wA[2][2];
  wA[0][0] = *(const f32x4*)(Wl);
  wA[0][1] = *(const f32x4*)(Wl + 4);
#pragma unroll
  for (int ks = 0; ks < 16; ++ks) {
    const int cur = ks & 1, nxt = cur ^ 1;
    if (ks < 15) {
      wA[nxt][0] = *(const f32x4*)(Wl + (ks + 1) * 32);
      wA[nxt][1] = *(const f32x4*)(Wl + (ks + 1) * 32 + 4);
    }
    short8 wf;
    unsigned* wfu = (unsigned*)&wf;
    wfu[0] = cvt_pk_bf16(wA[cur][0][0], wA[cur][0][1]);
    wfu[1] = cvt_pk_bf16(wA[cur][0][2], wA[cur][0][3]);
    wfu[2] = cvt_pk_bf16(wA[cur][1][0], wA[cur][1][1]);
    wfu[3] = cvt_pk_bf16(wA[cur][1][2], wA[cur][1][3]);
    const int k0 = ks * 32;
    short8 e0 = *(const short8*)(El + k0);
#pragma unroll
    for (int mt = 0; mt < MT; ++mt) {
      const short8 ecur = e0;
      if (mt < MT - 1) e0 = *(const short8*)(El + (mt + 1) * 16 * LDSW + k0);
      acc[mt][0] = __builtin_amdgcn_mfma_f32_16x16x32_bf16(wf, ecur, acc[mt][0], 0, 0, 0);
    }
  }
}

// relu(acc + bias[outcol]) -> bf16 -> LDS, 8B vector writes (edge layers).
template <int MT, int NT>
__device__ inline void store_relu_lds(short* E, const float* __restrict__ bias,
                                      int lane, int nbase, f32x4 (&acc)[MT][NT]) {
  const int mrow = lane & 15, kg = lane >> 4;
#pragma unroll
  for (int nt = 0; nt < NT; ++nt) {
    const int oc = nbase + nt * 16 + kg * 4;
    const float4 bs = *(const float4*)(bias + oc);
#pragma unroll
    for (int mt = 0; mt < MT; ++mt) {
      uint2 s = relu_pack4(acc[mt][nt][0] + bs.x, acc[mt][nt][1] + bs.y,
                           acc[mt][nt][2] + bs.z, acc[mt][nt][3] + bs.w);
      *(uint2*)&E[(mt * 16 + mrow) * LDSW + oc] = s;
    }
  }
}

// ---------------- node stage: 3 col-tiled kernels, fp32-direct W ----------
// MODE 1: X=bv fp32 -> f1 = relu(bv@Wa^T + ba + xy@Wxy^T + bxy) -> bf16.
//         ALSO converts edge weights (Wcb,Wcc tiled + Wout) fp32->bf16.
// MODE 2: X=f1 bf16 -> f2 = relu(f1@Wb^T + bb) -> bf16
// MODE 3: X=f2 bf16 -> u = f2@W1^T, v = f2@W2^T (Wca stride 1024) -> fp32
template <int MODE>
__global__ __launch_bounds__(256, 4) void node_layer(
    const void* __restrict__ Xin, const float* __restrict__ W,
    const float* __restrict__ bias, const float* __restrict__ xy,
    const float* __restrict__ Wxy, const float* __restrict__ bxy,
    void* __restrict__ Yout, float* __restrict__ vout, int colTiles,
    const float* __restrict__ Wcb, const float* __restrict__ Wcc,
    const float* __restrict__ Wout, short* __restrict__ edgeW) {
  __shared__ short X[64 * LDSW];
  __shared__ float xyl[128];
  const int tid = threadIdx.x, lane = tid & 63, wave = tid >> 6;
  const int rt = blockIdx.x / colTiles, ct = blockIdx.x % colTiles;
  const int row0 = rt * 64, c0 = ct * 64;
  const int mrow = lane & 15, kg = lane >> 4;

  if (MODE == 1) {
    // folded former prep: convert edge weights only (~86 elems/thread)
    const int M = 262144;
    const int gtid = blockIdx.x * blockDim.x + tid;
    const int gstride = gridDim.x * blockDim.x;
    for (int i = gtid; i < 2 * M + 1024; i += gstride) {
      float x; int dst;
      if (i < M) {
        const int c = i >> 9, k = i & 511;
        x = Wcb[i]; dst = wtile_off(c, k);
      } else if (i < 2 * M) {
        const int t = i - M, c = t >> 9, k = t & 511;
        x = Wcc[t]; dst = M + wtile_off(c, k);
      } else {
        x = Wout[i - 2 * M]; dst = i;
      }
      edgeW[dst] = (short)f2bf(x);
    }
  }

  if (MODE == 1) {
    const float* bv = (const float*)Xin;
    const int hc = (tid & 127) * 4, m0 = tid >> 7;
    for (int m = m0; m < 64; m += 2) {
      const float4 t = *(const float4*)(bv + (row0 + m) * 512 + hc);
      uint2 s;
      s.x = cvt_pk_bf16(t.x, t.y);
      s.y = cvt_pk_bf16(t.z, t.w);
      *(uint2*)&X[m * LDSW + hc] = s;
    }
    if (tid < 128) xyl[tid] = xy[row0 * 2 + tid];
  } else {
    const short* xb = (const short*)Xin;
    const int hc = (tid & 63) * 8, m0 = tid >> 6;
    for (int m = m0; m < 64; m += 4)
      *(short8*)&X[m * LDSW + hc] = *(const short8*)(xb + (row0 + m) * 512 + hc);
  }
  __syncthreads();

  const int nbase = c0 + wave * 16;
  f32x4 acc[4][1];
  zero_acc<4, 1>(acc);

  if (MODE == 3) {
    // u-half cols 0..511 at Wca[c*1024+k]; v-half cols 512..1023 at
    // Wca[(c-512)*1024 + 512 + k].  Block-uniform half (c0 mult of 64).
    const float* Wbase = (c0 < 512) ? W : (W + 512);
    const int colbase = (c0 < 512) ? nbase : (nbase - 512);
    gemm_kloop_wf32<4, 1024>(X, Wbase, lane, colbase, acc);
  } else {
    gemm_kloop_wf32<4, 512>(X, W, lane, nbase, acc);
  }

  const int oc = nbase + kg * 4;
  if (MODE == 3) {
    float* u = (float*)Yout;
#pragma unroll
    for (int mt = 0; mt < 4; ++mt) {
      const int row = row0 + mt * 16 + mrow;
      if (oc < 512) *(f32x4*)&u[row * 512 + oc] = acc[mt][0];     // block-uniform branch
      else          *(f32x4*)&vout[row * 512 + oc - 512] = acc[mt][0];
    }
  } else {
    short* Y = (short*)Yout;
    const float4 bs = *(const float4*)(bias + oc);
    float b2[4] = {0.f, 0.f, 0.f, 0.f}, w0[4], w1[4];
    if (MODE == 1) {
      const float4 t = *(const float4*)(bxy + oc);
      b2[0] = t.x; b2[1] = t.y; b2[2] = t.z; b2[3] = t.w;
#pragma unroll
      for (int r = 0; r < 4; ++r) { w0[r] = Wxy[(oc + r) * 2]; w1[r] = Wxy[(oc + r) * 2 + 1]; }
    }
#pragma unroll
    for (int mt = 0; mt < 4; ++mt) {
      const int row = mt * 16 + mrow;
      float xv[4];
#pragma unroll
      for (int r = 0; r < 4; ++r) {
        xv[r] = acc[mt][0][r] + ((const float*)&bs)[r];
        if (MODE == 1) xv[r] += b2[r] + xyl[row * 2] * w0[r] + xyl[row * 2 + 1] * w1[r];
      }
      uint2 s = relu_pack4(xv[0], xv[1], xv[2], xv[3]);
      *(uint2*)&Y[(row0 + row) * 512 + oc] = s;
    }
  }
}

// ---------------- edge stage: fused E0 -> E1 -> E2 -> out ----------------
// 144-row tiles (3 i x 48 j): LDS 158,976 B -> 1 block/CU, 8 waves.
// 1024 blocks = exactly 4 full rounds of 256 CUs. W/CU = 4.1 MB.
__global__ __launch_bounds__(512, 2) void edge_kernel(
    const float* __restrict__ u, const float* __restrict__ v,
    const short* __restrict__ Wcb, const short* __restrict__ Wcc,
    const short* __restrict__ Wout,
    const float* __restrict__ bca, const float* __restrict__ bcb,
    const float* __restrict__ bcc, const float* __restrict__ bout,
    float* __restrict__ out) {
  __shared__ short A[144 * LDSW];      // 149,760 B
  __shared__ float red[144 * 2 * 8];   //   9,216 B
  const int tid = threadIdx.x, lane = tid & 63, wave = tid >> 6;
  const int blk = blockIdx.x;
  const int b = blk >> 8, rem = blk & 255, ip = rem >> 2, jt = rem & 3;
  const float* urow0 = u + (b * 192 + jt * 48) * 512;        // row m: j = jt*48 + m%48
  const float* vrow0 = v + (b * 192 + ip * 3) * 512;         // row m: i = ip*3 + m/48

  {  // Phase 0: E0 = relu(u[j] + v[i] + b_ca) -> bf16 LDS.  (v+b_ca) hoisted,
     // convert packed (v_cvt_pk_bf16_f32).
    const int hc = (tid & 127) * 4, m0 = tid >> 7;
    const float4 bb = *(const float4*)(bca + hc);
    const float4 a0 = *(const float4*)(vrow0 + hc);
    const float4 a1 = *(const float4*)(vrow0 + 512 + hc);
    const float4 a2 = *(const float4*)(vrow0 + 1024 + hc);
    float4 vb0, vb1, vb2;
    vb0.x = a0.x + bb.x; vb0.y = a0.y + bb.y; vb0.z = a0.z + bb.z; vb0.w = a0.w + bb.w;
    vb1.x = a1.x + bb.x; vb1.y = a1.y + bb.y; vb1.z = a1.z + bb.z; vb1.w = a1.w + bb.w;
    vb2.x = a2.x + bb.x; vb2.y = a2.y + bb.y; vb2.z = a2.z + bb.z; vb2.w = a2.w + bb.w;
#pragma unroll 4
    for (int m = m0; m < 144; m += 4) {
      const int ii = (m >= 96) ? 2 : (m >= 48 ? 1 : 0);
      const int jj = m - ii * 48;
      const float4 vv = (ii == 0) ? vb0 : (ii == 1) ? vb1 : vb2;
      const float4 uu = *(const float4*)(urow0 + jj * 512 + hc);
      uint2 s = relu_pack4(uu.x + vv.x, uu.y + vv.y, uu.z + vv.z, uu.w + vv.w);
      *(uint2*)&A[m * LDSW + hc] = s;
    }
  }
  __syncthreads();

  const int nbase = wave * 64;
  f32x4 acc[9][4];

  // layer cb
  zero_acc<9, 4>(acc);
  gemm_kloop<9, 4>(A, Wcb, lane, nbase, acc);
  __syncthreads();                 // all waves done reading E0
  store_relu_lds<9, 4>(A, bcb, lane, nbase, acc);
  __syncthreads();

  // layer cc
  zero_acc<9, 4>(acc);
  gemm_kloop<9, 4>(A, Wcc, lane, nbase, acc);
  __syncthreads();
  store_relu_lds<9, 4>(A, bcc, lane, nbase, acc);
  __syncthreads();

  // final: out = E2 @ Wout^T + bout.  k-split across 8 waves, n padded 2->16.
  f32x4 oacc[9];
#pragma unroll
  for (int mt = 0; mt < 9; ++mt) { f32x4 z = {0.f, 0.f, 0.f, 0.f}; oacc[mt] = z; }
  const int n = lane & 15, kg2 = lane >> 4;
#pragma unroll
  for (int kk = 0; kk < 2; ++kk) {
    const int k0 = wave * 64 + kk * 32 + kg2 * 8;
    short8 bf = {0, 0, 0, 0, 0, 0, 0, 0};
    if (n < 2) bf = *(const short8*)(Wout + n * 512 + k0);
#pragma unroll
    for (int mt = 0; mt < 9; ++mt) {
      const short8 af = *(const short8*)(A + (mt * 16 + n) * LDSW + k0);
      oacc[mt] = __builtin_amdgcn_mfma_f32_16x16x32_bf16(af, bf, oacc[mt], 0, 0, 0);
    }
  }
  if (n < 2) {
#pragma unroll
    for (int mt = 0; mt < 9; ++mt)
#pragma unroll
      for (int r = 0; r < 4; ++r) {
        const int row = mt * 16 + kg2 * 4 + r;
        red[(row * 2 + n) * 8 + wave] = oacc[mt][r];
      }
  }
  __syncthreads();
  if (tid < 288) {
    const int row = tid >> 1, o = tid & 1;
    float s = bout[o];
#pragma unroll
    for (int w = 0; w < 8; ++w) s += red[(row * 2 + o) * 8 + w];
    const int ii = (row >= 96) ? 2 : (row >= 48 ? 1 : 0);
    const int jj = row - ii * 48;
    out[((b * 192 + ip * 3 + ii) * 192 + jt * 48 + jj) * 2 + o] = s;
  }
}

extern "C" void kernel_launch(void* const* d_in, const int* in_sizes, int n_in,
                              void* d_out, int out_size, void* d_ws, size_t ws_size,
                              hipStream_t stream) {
  const float* bv   = (const float*)d_in[0];
  const float* xy   = (const float*)d_in[1];
  const float* Wxy  = (const float*)d_in[2];
  const float* bxy  = (const float*)d_in[3];
  const float* Wa   = (const float*)d_in[4];
  const float* ba   = (const float*)d_in[5];
  const float* Wb   = (const float*)d_in[6];
  const float* bb   = (const float*)d_in[7];
  const float* Wca  = (const float*)d_in[8];
  const float* bca  = (const float*)d_in[9];
  const float* Wcb  = (const float*)d_in[10];
  const float* bcb  = (const float*)d_in[11];
  const float* Wcc  = (const float*)d_in[12];
  const float* bcc  = (const float*)d_in[13];
  const float* Wout = (const float*)d_in[14];
  const float* bout = (const float*)d_in[15];
  float* out = (float*)d_out;

  // ws layout (bytes), M = 262144 elems:
  //   edgeW shorts: WcbB [0, M), WccB [M, 2M), WoutB [2M, 2M+1024)
  //     -> bytes [0, 1,050,624)
  //   f2 bf16 @ 1,050,624 (786,432 B) end 1,837,056
  //   f1 bf16 @ 1,837,056 (786,432 B); u fp32 aliases f1 region
  //     (f1 dead after node2 reads it; node3 writes u) end 3,409,920
  //   v  fp32 @ 3,409,920 (1,572,864 B) end 4,982,784  (< 7,079,936 prior cap)
  short* S = (short*)d_ws;
  char* base = (char*)d_ws;
  short* WcbB  = S;
  short* WccB  = S + 262144;
  short* WoutB = S + 524288;
  short* f2 = (short*)(base + 1050624);
  short* f1 = (short*)(base + 1837056);
  float* u  = (float*)(base + 1837056);
  float* v  = (float*)(base + 3409920);

  node_layer<1><<<96, 256, 0, stream>>>(bv, Wa, ba, xy, Wxy, bxy, f1, nullptr, 8,
                                        Wcb, Wcc, Wout, S);
  node_layer<2><<<96, 256, 0, stream>>>(f1, Wb, bb, nullptr, nullptr, nullptr, f2,
                                        nullptr, 8, nullptr, nullptr, nullptr, nullptr);
  node_layer<3><<<192, 256, 0, stream>>>(f2, Wca, nullptr, nullptr, nullptr, nullptr,
                                         u, v, 16, nullptr, nullptr, nullptr, nullptr);
  edge_kernel<<<1024, 512, 0, stream>>>(u, v, WcbB, WccB, WoutB, bca, bcb, bcc, bout, out);
}